// Round 18
// baseline (109.426 us; speedup 1.0000x reference)
//
#include <hip/hip_runtime.h>
#include <hip/hip_bf16.h>

typedef __attribute__((ext_vector_type(8))) short bf16x8;
typedef __attribute__((ext_vector_type(4))) float f32x4;

#define MFMA_BF16 __builtin_amdgcn_mfma_f32_16x16x32_bf16

#define GLDS16(gp, lp)                                                        \
  __builtin_amdgcn_global_load_lds(                                           \
      (const __attribute__((address_space(1))) void*)(gp),                    \
      (__attribute__((address_space(3))) void*)(lp), 16, 0, 0)

__device__ __forceinline__ unsigned pk2(float a, float b) {
  __hip_bfloat162 t = __float22bfloat162_rn(make_float2(a, b));
  return *reinterpret_cast<unsigned*>(&t);
}
__device__ __forceinline__ unsigned short f2bf_hw(float f) {
  __hip_bfloat16 h = __float2bfloat16(f);
  return *reinterpret_cast<unsigned short*>(&h);
}
__device__ __forceinline__ float tanh_f(float x) {
  return 1.f - 2.f * __builtin_amdgcn_rcpf(1.f + __expf(2.f * x));
}

// ---------------------------------------------------------------------------
// k0: one-time weight conversion to frag-major bf16 tables in d_ws. (= R17)
// ---------------------------------------------------------------------------
__global__ void k0_conv(const float* __restrict__ W0, const float* __restrict__ Wfw,
                        const float* __restrict__ Wbw, unsigned short* __restrict__ wfrag,
                        unsigned short* __restrict__ wlstm) {
  int gid = blockIdx.x * 256 + threadIdx.x;
  if (gid < 4096) {
    int f = gid >> 6, l = gid & 63;
    int k0 = (f >> 2) * 32 + ((l >> 4) << 3);
    int n = (f & 3) * 16 + (l & 15);
    bf16x8 v;
#pragma unroll
    for (int j = 0; j < 8; ++j) v[j] = (short)f2bf_hw(W0[(k0 + j) * 64 + n]);
    *(bf16x8*)(wfrag + gid * 8) = v;
  } else if (gid < 12288) {
    int g2 = gid - 4096;
    const float* W = (g2 < 4096) ? Wfw : Wbw;
    int f = (g2 & 4095) >> 6, l = g2 & 63;
    int wv = f >> 4, gate = (f >> 2) & 3, kf = f & 3;
    int col = gate * 64 + wv * 16 + (l & 15);
    int kr = kf * 32 + ((l >> 4) << 3);
    bf16x8 v;
#pragma unroll
    for (int j = 0; j < 8; ++j) v[j] = (short)f2bf_hw(W[(kr + j) * 256 + col]);
    *(bf16x8*)(wlstm + g2 * 8) = v;
  }
}

// ---------------------------------------------------------------------------
// K1: EXACTLY the R17 kernel (R8 structure + XCD swizzle).
// ---------------------------------------------------------------------------
__global__ __launch_bounds__(256, 3) void k_dense_ln(
    const float* __restrict__ obs, const unsigned short* __restrict__ wfrag,
    const float* __restrict__ b0, const float* __restrict__ gam,
    const float* __restrict__ bet, unsigned short* __restrict__ xout) {
  __shared__ __align__(16) char lds[49152];  // 3 x 16 KB
  const int tid = threadIdx.x, w = tid >> 6, l = tid & 63;
  const int g = l >> 4, c = l & 15;
  const int tile = (blockIdx.x & 7) * 256 + (blockIdx.x >> 3);  // XCD swizzle
  const long blk64 = (long)tile * 64;
  const long rb = blk64 + w * 16;

  float b0v[4], gv[4], bv[4];
#pragma unroll
  for (int nt = 0; nt < 4; ++nt) {
    int col = nt * 16 + c;
    b0v[nt] = b0[col]; gv[nt] = gam[col]; bv[nt] = bet[col];
  }
  const unsigned short* wfl = wfrag + l * 8;
  const char* gB = (const char*)obs + blk64 * 2048;

  const int rlo = w * 4 + g;
  asm volatile("s_waitcnt vmcnt(0)" ::: "memory");

#define K1_STAGE(q)                                                           \
  {                                                                           \
    _Pragma("unroll") for (int i = 0; i < 4; ++i) {                           \
      int row_ = i * 16 + rlo;                                                \
      const char* gp_ = gB + (long)row_ * 2048 + (q) * 256 +                  \
                        (long)((c ^ rlo) * 16);                               \
      char* lp_ = lds + ((q) % 3) * 16384 + (i * 4096 + (w * 64 + l) * 16);   \
      GLDS16(gp_, lp_);                                                       \
    }                                                                         \
  }

  K1_STAGE(0);
  K1_STAGE(1);
  K1_STAGE(2);

  f32x4 acc[4];
#pragma unroll
  for (int nt = 0; nt < 4; ++nt) acc[nt] = (f32x4){0.f, 0.f, 0.f, 0.f};

#pragma unroll
  for (int q = 0; q < 8; ++q) {
    constexpr int VW[8] = {8, 16, 24, 24, 24, 24, 20, 16};
    asm volatile("s_waitcnt vmcnt(%0)" :: "i"(VW[q]) : "memory");
    __builtin_amdgcn_s_barrier();
    __builtin_amdgcn_sched_barrier(0);

    const char* rowb = lds + (q % 3) * 16384 + (w * 16 + c) * 256;
#pragma unroll
    for (int kf = 0; kf < 2; ++kf) {
      int fb = (q * 2 + kf) * 4;
      bf16x8 B0 = *(const bf16x8*)(wfl + (fb + 0) * 512);
      bf16x8 B1 = *(const bf16x8*)(wfl + (fb + 1) * 512);
      bf16x8 B2 = *(const bf16x8*)(wfl + (fb + 2) * 512);
      bf16x8 B3 = *(const bf16x8*)(wfl + (fb + 3) * 512);
      int u0 = kf * 8 + g * 2;
      float4 f0 = *(const float4*)(rowb + ((u0 + 0) ^ c) * 16);
      float4 f1 = *(const float4*)(rowb + ((u0 + 1) ^ c) * 16);
      union { bf16x8 v; unsigned u[4]; } af;
      af.u[0] = pk2(f0.x, f0.y); af.u[1] = pk2(f0.z, f0.w);
      af.u[2] = pk2(f1.x, f1.y); af.u[3] = pk2(f1.z, f1.w);
      acc[0] = MFMA_BF16(af.v, B0, acc[0], 0, 0, 0);
      acc[1] = MFMA_BF16(af.v, B1, acc[1], 0, 0, 0);
      acc[2] = MFMA_BF16(af.v, B2, acc[2], 0, 0, 0);
      acc[3] = MFMA_BF16(af.v, B3, acc[3], 0, 0, 0);
    }
    if (q < 5) {
      __builtin_amdgcn_s_barrier();
      __builtin_amdgcn_sched_barrier(0);
      K1_STAGE(q + 3);
    }
  }

  float vv[4][4], s1[4], s2[4];
#pragma unroll
  for (int r = 0; r < 4; ++r) { s1[r] = 0.f; s2[r] = 0.f; }
#pragma unroll
  for (int nt = 0; nt < 4; ++nt)
#pragma unroll
    for (int r = 0; r < 4; ++r) {
      float val = acc[nt][r] + b0v[nt];
      vv[nt][r] = val; s1[r] += val; s2[r] += val * val;
    }
#pragma unroll
  for (int r = 0; r < 4; ++r) {
#pragma unroll
    for (int m = 1; m <= 8; m <<= 1) {
      s1[r] += __shfl_xor(s1[r], m);
      s2[r] += __shfl_xor(s2[r], m);
    }
  }
  unsigned short* xw = (unsigned short*)lds + w * 1024;
#pragma unroll
  for (int r = 0; r < 4; ++r) {
    float mu = s1[r] * 0.015625f;
    float var = s2[r] * 0.015625f - mu * mu;
    float inv = rsqrtf(var + 1e-12f);
    int row = g * 4 + r;
#pragma unroll
    for (int nt = 0; nt < 4; ++nt) {
      float xn = (vv[nt][r] - mu) * inv * gv[nt] + bv[nt];
      xw[(row * 64 + nt * 16 + c) ^ (g << 3)] = f2bf_hw(fmaxf(xn, 0.f));
    }
  }
#pragma unroll
  for (int m2 = 0; m2 < 2; ++m2) {
    int m = m2 * 64 + l;
    int row = m >> 3, u8 = m & 7;
    bf16x8 v = *(const bf16x8*)(xw + ((row * 64 + u8 * 8) ^ ((row >> 2) << 3)));
    *(bf16x8*)(xout + (rb + row) * 64 + u8 * 8) = v;
  }
}

// ---------------------------------------------------------------------------
// K2 MERGED-DIR: 256 blocks x 256 thr, 1 block/CU (104 KB LDS). Both
// directions of 16 seqs in one block: x staged ONCE (time-ordered slots,
// stage-all + single vmcnt(0) -> no in-loop vmcnt logic), fw/bw chains are
// independent -> intra-wave ILP replaces TLP. Projection of h(t-1) at step-t
// top reuses the Ah regs (wave-uniform MFMA), result -> LDS pl, coalesced
// flush at end. hl per dir double-buffered.
// ---------------------------------------------------------------------------
__global__ __launch_bounds__(256, 1) void k_lstm(
    const unsigned short* __restrict__ x, const unsigned short* __restrict__ wlstm,
    const float* __restrict__ bfw, const float* __restrict__ bbw,
    const float* __restrict__ Wc, const float* __restrict__ bc,
    float* __restrict__ out) {
  __shared__ __align__(16) char xl[65536];        // 32 slots x 2KB, slot t = x(t)
  __shared__ unsigned short hl[2][2048];          // [dir][pbuf*1024+off], 8 KB
  __shared__ float pl[2][16 * 32 * 8];            // [dir][s][tp][a], 32 KB
  const int tid = threadIdx.x, w = tid >> 6, l = tid & 63;
  const int g = l >> 4, c = l & 15;
  const int bid = blockIdx.x;
  const int g2 = (bid & 7) * 32 + (bid >> 3);     // XCD-matched to K1 tiles
  const int sq = g2 * 16;

  // weights for BOTH dirs
  bf16x8 Bf[2][4][4];
  float bz[2][4];
#pragma unroll
  for (int d = 0; d < 2; ++d) {
    const unsigned short* wl = wlstm + ((long)d * 4096 + w * 16 * 64) * 8;
#pragma unroll
    for (int gate = 0; gate < 4; ++gate) {
#pragma unroll
      for (int kf = 0; kf < 4; ++kf)
        Bf[d][gate][kf] = *(const bf16x8*)(wl + ((gate * 4 + kf) * 64 + l) * 8);
      bz[d][gate] = (d ? bbw : bfw)[gate * 64 + w * 16 + c];
    }
  }

  bf16x8 Pc[2];
#pragma unroll
  for (int kf = 0; kf < 2; ++kf)
#pragma unroll
    for (int j = 0; j < 8; ++j) Pc[kf][j] = 0;
  float bcv = 0.f;
  if (c < 8) {
#pragma unroll
    for (int kf = 0; kf < 2; ++kf)
#pragma unroll
      for (int j = 0; j < 8; ++j)
        Pc[kf][j] = (short)f2bf_hw(Wc[(kf * 32 + g * 8 + j) * 8 + c]);
    bcv = bc[c];
  }

  asm volatile("s_waitcnt vmcnt(0)" ::: "memory");

  // stage ALL 32 slots in TIME order (slot tt = x at time tt)
  const int ss = l >> 3, sc = l & 7;
#pragma unroll
  for (int j = 0; j < 8; ++j) {
    int tt = w * 8 + j;
#pragma unroll
    for (int p = 0; p < 2; ++p) {
      int s = p * 8 + ss;
      const char* gp = (const char*)x +
          ((long)(sq + s) * 32 + tt) * 128 + (long)(sc ^ (s & 7)) * 16;
      char* lp = xl + tt * 2048 + p * 1024;
      GLDS16(gp, lp);
    }
  }

  for (int i = tid; i < 2048; i += 256) ((unsigned*)hl)[i] = 0u;  // both dirs
  float cs[2][4] = {{0.f, 0.f, 0.f, 0.f}, {0.f, 0.f, 0.f, 0.f}};

  asm volatile("s_waitcnt vmcnt(0)" ::: "memory");
  asm volatile("s_waitcnt lgkmcnt(0)" ::: "memory");
  __builtin_amdgcn_s_barrier();
  __builtin_amdgcn_sched_barrier(0);

  const int hq = w >> 1;
  const int hgp = ((w & 1) * 2 + (c >> 3)) * 16;
  const int hlo = c & 7;
  const int hoff = (hq * 64 + hgp) * 8 + hlo;  // + (4g+r)*8 per cell

  // accx(0): fw from slot 0, bw from slot 31
  f32x4 accx[2][4];
#pragma unroll
  for (int d = 0; d < 2; ++d) {
    const char* xt = xl + (d ? 31 : 0) * 2048 + c * 128;
    bf16x8 Ax0 = *(const bf16x8*)(xt + (long)((g) ^ (c & 7)) * 16);
    bf16x8 Ax1 = *(const bf16x8*)(xt + (long)((4 + g) ^ (c & 7)) * 16);
#pragma unroll
    for (int gate = 0; gate < 4; ++gate) {
      f32x4 b = (f32x4){bz[d][gate], bz[d][gate], bz[d][gate], bz[d][gate]};
      accx[d][gate] = MFMA_BF16(Ax1, Bf[d][gate][1],
                                MFMA_BF16(Ax0, Bf[d][gate][0], b, 0, 0, 0),
                                0, 0, 0);
    }
  }

  int p = 0;
#pragma unroll 2
  for (int t = 0; t < 32; ++t) {
    bf16x8 Ah[2][2];
#pragma unroll
    for (int d = 0; d < 2; ++d) {
      const char* hb = (const char*)&hl[d][0] + p * 2048;
      Ah[d][0] = *(const bf16x8*)(hb + l * 16);
      Ah[d][1] = *(const bf16x8*)(hb + 1024 + l * 16);
    }

    // projection of h(t-1) (both dirs) on the just-loaded Ah regs ->
    // wave-uniform MFMAs; wave 0 writes pl (cheap LDS store, no straggle)
    if (t >= 1 && w == 0) {
#pragma unroll
      for (int d = 0; d < 2; ++d) {
        f32x4 pa = (f32x4){0.f, 0.f, 0.f, 0.f};
        pa = MFMA_BF16(Ah[d][0], Pc[0], pa, 0, 0, 0);
        pa = MFMA_BF16(Ah[d][1], Pc[1], pa, 0, 0, 0);
        if (c < 8) {
          int tp = d ? 32 - t : t - 1;
#pragma unroll
          for (int r = 0; r < 4; ++r)
            pl[d][(4 * g + r) * 256 + tp * 8 + c] = tanh_f(pa[r] + bcv);
        }
      }
    }

    f32x4 acc[2][4];
#pragma unroll
    for (int d = 0; d < 2; ++d)
#pragma unroll
      for (int gate = 0; gate < 4; ++gate)
        acc[d][gate] = MFMA_BF16(Ah[d][1], Bf[d][gate][3],
                                 MFMA_BF16(Ah[d][0], Bf[d][gate][2],
                                           accx[d][gate], 0, 0, 0),
                                 0, 0, 0);

    // accx(t+1): fw slot t+1, bw slot 30-t
    if (t + 1 < 32) {
#pragma unroll
      for (int d = 0; d < 2; ++d) {
        const char* xt = xl + (d ? 30 - t : t + 1) * 2048 + c * 128;
        bf16x8 Ax0 = *(const bf16x8*)(xt + (long)((g) ^ (c & 7)) * 16);
        bf16x8 Ax1 = *(const bf16x8*)(xt + (long)((4 + g) ^ (c & 7)) * 16);
#pragma unroll
        for (int gate = 0; gate < 4; ++gate) {
          f32x4 b = (f32x4){bz[d][gate], bz[d][gate], bz[d][gate], bz[d][gate]};
          accx[d][gate] = MFMA_BF16(Ax1, Bf[d][gate][1],
                                    MFMA_BF16(Ax0, Bf[d][gate][0], b, 0, 0, 0),
                                    0, 0, 0);
        }
      }
    }

    // rcp-merged gates, 8 independent cells (4 fw + 4 bw)
    const int wb = (p ^ 1) * 1024;
#pragma unroll
    for (int d = 0; d < 2; ++d)
#pragma unroll
      for (int r = 0; r < 4; ++r) {
        float ei = __expf(-acc[d][0][r]);
        float ej = __expf(2.f * acc[d][1][r]);
        float ef = __expf(-(acc[d][2][r] + 1.f));
        float eo = __expf(-acc[d][3][r]);
        float p12 = (1.f + ei) * (1.f + ej);
        float r3 = __builtin_amdgcn_rcpf(p12 * (1.f + ef));
        float it = (ej - 1.f) * (1.f + ef) * r3;
        float sf = p12 * r3;
        cs[d][r] = cs[d][r] * sf + it;
        float ec = __expf(2.f * cs[d][r]);
        float r2 = __builtin_amdgcn_rcpf((1.f + eo) * (1.f + ec));
        hl[d][wb + hoff + (4 * g + r) * 8] = f2bf_hw((ec - 1.f) * r2);
      }

    asm volatile("s_waitcnt lgkmcnt(0)" ::: "memory");
    __builtin_amdgcn_s_barrier();
    __builtin_amdgcn_sched_barrier(0);
    p ^= 1;
  }

  // final projection: h(31) in hl[d][p]
  if (w == 0) {
#pragma unroll
    for (int d = 0; d < 2; ++d) {
      const char* hb = (const char*)&hl[d][0] + p * 2048;
      bf16x8 Ph0 = *(const bf16x8*)(hb + l * 16);
      bf16x8 Ph1 = *(const bf16x8*)(hb + 1024 + l * 16);
      f32x4 pa = (f32x4){0.f, 0.f, 0.f, 0.f};
      pa = MFMA_BF16(Ph0, Pc[0], pa, 0, 0, 0);
      pa = MFMA_BF16(Ph1, Pc[1], pa, 0, 0, 0);
      if (c < 8) {
        int tp = d ? 0 : 31;
#pragma unroll
        for (int r = 0; r < 4; ++r)
          pl[d][(4 * g + r) * 256 + tp * 8 + c] = tanh_f(pa[r] + bcv);
      }
    }
  }

  // flush pl -> out (both dirs), coalesced float4 stores
  asm volatile("s_waitcnt lgkmcnt(0)" ::: "memory");
  __builtin_amdgcn_s_barrier();
#pragma unroll
  for (int i = 0; i < 8; ++i) {
    int fi = tid + i * 256;                // float4 index over [d][s][t][a]
    int d = fi >> 10, rem = fi & 1023;
    int s = rem >> 6, r2 = rem & 63;
    int t2 = r2 >> 1, a4 = (r2 & 1) * 4;
    float4 v = *(const float4*)(&pl[d][0] + s * 256 + t2 * 8 + a4);
    *(float4*)(out + ((long)(d * 4096 + sq + s) * 32 + t2) * 8 + a4) = v;
  }
}

extern "C" void kernel_launch(void* const* d_in, const int* in_sizes, int n_in,
                              void* d_out, int out_size, void* d_ws, size_t ws_size,
                              hipStream_t stream) {
  const float* obs = (const float*)d_in[0];
  const float* W0  = (const float*)d_in[1];
  const float* b0  = (const float*)d_in[2];
  const float* gam = (const float*)d_in[3];
  const float* bet = (const float*)d_in[4];
  const float* Wfw = (const float*)d_in[5];
  const float* bfw = (const float*)d_in[6];
  const float* Wbw = (const float*)d_in[7];
  const float* bbw = (const float*)d_in[8];
  const float* Wc  = (const float*)d_in[9];
  const float* bc  = (const float*)d_in[10];
  float* out = (float*)d_out;

  unsigned short* wfrag = (unsigned short*)d_ws;       // 64 KB
  unsigned short* wlstm = wfrag + 4096 * 8;            // 128 KB
  unsigned short* xbf   = wlstm + 8192 * 8;            // 16.78 MB

  k0_conv<<<48, 256, 0, stream>>>(W0, Wfw, Wbw, wfrag, wlstm);
  k_dense_ln<<<2048, 256, 0, stream>>>(obs, wfrag, b0, gam, bet, xbf);
  k_lstm<<<256, 256, 0, stream>>>(xbf, wlstm, bfw, bbw, Wc, bc, out);
}

// Round 19
// 97.170 us; speedup vs baseline: 1.1261x; 1.1261x over previous
//
#include <hip/hip_runtime.h>
#include <hip/hip_bf16.h>

typedef __attribute__((ext_vector_type(8))) short bf16x8;
typedef __attribute__((ext_vector_type(4))) float f32x4;

#define MFMA_BF16 __builtin_amdgcn_mfma_f32_16x16x32_bf16

#define GLDS16(gp, lp)                                                        \
  __builtin_amdgcn_global_load_lds(                                           \
      (const __attribute__((address_space(1))) void*)(gp),                    \
      (__attribute__((address_space(3))) void*)(lp), 16, 0, 0)

__device__ __forceinline__ unsigned pk2(float a, float b) {
  __hip_bfloat162 t = __float22bfloat162_rn(make_float2(a, b));
  return *reinterpret_cast<unsigned*>(&t);
}
__device__ __forceinline__ unsigned short f2bf_hw(float f) {
  __hip_bfloat16 h = __float2bfloat16(f);
  return *reinterpret_cast<unsigned short*>(&h);
}
__device__ __forceinline__ float tanh_f(float x) {
  return 1.f - 2.f * __builtin_amdgcn_rcpf(1.f + __expf(2.f * x));
}

// ---------------------------------------------------------------------------
// k0: one-time weight conversion to frag-major bf16 tables in d_ws.
// ---------------------------------------------------------------------------
__global__ void k0_conv(const float* __restrict__ W0, const float* __restrict__ Wfw,
                        const float* __restrict__ Wbw, unsigned short* __restrict__ wfrag,
                        unsigned short* __restrict__ wlstm) {
  int gid = blockIdx.x * 256 + threadIdx.x;
  if (gid < 4096) {
    int f = gid >> 6, l = gid & 63;
    int k0 = (f >> 2) * 32 + ((l >> 4) << 3);
    int n = (f & 3) * 16 + (l & 15);
    bf16x8 v;
#pragma unroll
    for (int j = 0; j < 8; ++j) v[j] = (short)f2bf_hw(W0[(k0 + j) * 64 + n]);
    *(bf16x8*)(wfrag + gid * 8) = v;
  } else if (gid < 12288) {
    int g2 = gid - 4096;
    const float* W = (g2 < 4096) ? Wfw : Wbw;
    int f = (g2 & 4095) >> 6, l = g2 & 63;
    int wv = f >> 4, gate = (f >> 2) & 3, kf = f & 3;
    int col = gate * 64 + wv * 16 + (l & 15);
    int kr = kf * 32 + ((l >> 4) << 3);
    bf16x8 v;
#pragma unroll
    for (int j = 0; j < 8; ++j) v[j] = (short)f2bf_hw(W[(kr + j) * 256 + col]);
    *(bf16x8*)(wlstm + g2 * 8) = v;
  }
}

// ---------------------------------------------------------------------------
// K1: R8 structure + XCD swizzle (best measured: part of the 97.5 us build).
// ---------------------------------------------------------------------------
__global__ __launch_bounds__(256, 3) void k_dense_ln(
    const float* __restrict__ obs, const unsigned short* __restrict__ wfrag,
    const float* __restrict__ b0, const float* __restrict__ gam,
    const float* __restrict__ bet, unsigned short* __restrict__ xout) {
  __shared__ __align__(16) char lds[49152];  // 3 x 16 KB
  const int tid = threadIdx.x, w = tid >> 6, l = tid & 63;
  const int g = l >> 4, c = l & 15;
  const int tile = (blockIdx.x & 7) * 256 + (blockIdx.x >> 3);  // XCD swizzle
  const long blk64 = (long)tile * 64;
  const long rb = blk64 + w * 16;

  float b0v[4], gv[4], bv[4];
#pragma unroll
  for (int nt = 0; nt < 4; ++nt) {
    int col = nt * 16 + c;
    b0v[nt] = b0[col]; gv[nt] = gam[col]; bv[nt] = bet[col];
  }
  const unsigned short* wfl = wfrag + l * 8;
  const char* gB = (const char*)obs + blk64 * 2048;

  const int rlo = w * 4 + g;
  asm volatile("s_waitcnt vmcnt(0)" ::: "memory");

#define K1_STAGE(q)                                                           \
  {                                                                           \
    _Pragma("unroll") for (int i = 0; i < 4; ++i) {                           \
      int row_ = i * 16 + rlo;                                                \
      const char* gp_ = gB + (long)row_ * 2048 + (q) * 256 +                  \
                        (long)((c ^ rlo) * 16);                               \
      char* lp_ = lds + ((q) % 3) * 16384 + (i * 4096 + (w * 64 + l) * 16);   \
      GLDS16(gp_, lp_);                                                       \
    }                                                                         \
  }

  K1_STAGE(0);
  K1_STAGE(1);
  K1_STAGE(2);

  f32x4 acc[4];
#pragma unroll
  for (int nt = 0; nt < 4; ++nt) acc[nt] = (f32x4){0.f, 0.f, 0.f, 0.f};

#pragma unroll
  for (int q = 0; q < 8; ++q) {
    constexpr int VW[8] = {8, 16, 24, 24, 24, 24, 20, 16};
    asm volatile("s_waitcnt vmcnt(%0)" :: "i"(VW[q]) : "memory");
    __builtin_amdgcn_s_barrier();
    __builtin_amdgcn_sched_barrier(0);

    const char* rowb = lds + (q % 3) * 16384 + (w * 16 + c) * 256;
#pragma unroll
    for (int kf = 0; kf < 2; ++kf) {
      int fb = (q * 2 + kf) * 4;
      bf16x8 B0 = *(const bf16x8*)(wfl + (fb + 0) * 512);
      bf16x8 B1 = *(const bf16x8*)(wfl + (fb + 1) * 512);
      bf16x8 B2 = *(const bf16x8*)(wfl + (fb + 2) * 512);
      bf16x8 B3 = *(const bf16x8*)(wfl + (fb + 3) * 512);
      int u0 = kf * 8 + g * 2;
      float4 f0 = *(const float4*)(rowb + ((u0 + 0) ^ c) * 16);
      float4 f1 = *(const float4*)(rowb + ((u0 + 1) ^ c) * 16);
      union { bf16x8 v; unsigned u[4]; } af;
      af.u[0] = pk2(f0.x, f0.y); af.u[1] = pk2(f0.z, f0.w);
      af.u[2] = pk2(f1.x, f1.y); af.u[3] = pk2(f1.z, f1.w);
      acc[0] = MFMA_BF16(af.v, B0, acc[0], 0, 0, 0);
      acc[1] = MFMA_BF16(af.v, B1, acc[1], 0, 0, 0);
      acc[2] = MFMA_BF16(af.v, B2, acc[2], 0, 0, 0);
      acc[3] = MFMA_BF16(af.v, B3, acc[3], 0, 0, 0);
    }
    if (q < 5) {
      __builtin_amdgcn_s_barrier();
      __builtin_amdgcn_sched_barrier(0);
      K1_STAGE(q + 3);
    }
  }

  float vv[4][4], s1[4], s2[4];
#pragma unroll
  for (int r = 0; r < 4; ++r) { s1[r] = 0.f; s2[r] = 0.f; }
#pragma unroll
  for (int nt = 0; nt < 4; ++nt)
#pragma unroll
    for (int r = 0; r < 4; ++r) {
      float val = acc[nt][r] + b0v[nt];
      vv[nt][r] = val; s1[r] += val; s2[r] += val * val;
    }
#pragma unroll
  for (int r = 0; r < 4; ++r) {
#pragma unroll
    for (int m = 1; m <= 8; m <<= 1) {
      s1[r] += __shfl_xor(s1[r], m);
      s2[r] += __shfl_xor(s2[r], m);
    }
  }
  unsigned short* xw = (unsigned short*)lds + w * 1024;
#pragma unroll
  for (int r = 0; r < 4; ++r) {
    float mu = s1[r] * 0.015625f;
    float var = s2[r] * 0.015625f - mu * mu;
    float inv = rsqrtf(var + 1e-12f);
    int row = g * 4 + r;
#pragma unroll
    for (int nt = 0; nt < 4; ++nt) {
      float xn = (vv[nt][r] - mu) * inv * gv[nt] + bv[nt];
      xw[(row * 64 + nt * 16 + c) ^ (g << 3)] = f2bf_hw(fmaxf(xn, 0.f));
    }
  }
#pragma unroll
  for (int m2 = 0; m2 < 2; ++m2) {
    int m = m2 * 64 + l;
    int row = m >> 3, u8 = m & 7;
    bf16x8 v = *(const bf16x8*)(xw + ((row * 64 + u8 * 8) ^ ((row >> 2) << 3)));
    *(bf16x8*)(xout + (rb + row) * 64 + u8 * 8) = v;
  }
}

// ---------------------------------------------------------------------------
// K2: R16 kernel + matching XCD swizzle (best measured: 97.5 us build).
// h(t) dual-written to hl (recurrence) + xl slot t (history); projection in
// a fully parallel epilogue; no stores in the loop's vmcnt FIFO.
// ---------------------------------------------------------------------------
__global__ __launch_bounds__(256, 2) void k_lstm(
    const unsigned short* __restrict__ x, const unsigned short* __restrict__ wlstm,
    const float* __restrict__ bfw, const float* __restrict__ bbw,
    const float* __restrict__ Wc, const float* __restrict__ bc,
    float* __restrict__ out) {
  __shared__ __align__(16) char xl[65536];   // 32 slots x 2KB: x(t), then h(t)
  __shared__ unsigned short hl[2 * 1024];
  const int tid = threadIdx.x, w = tid >> 6, l = tid & 63;
  const int g = l >> 4, c = l & 15;
  const int bid = blockIdx.x;
  const int kk = bid >> 3;
  const int dir = kk & 1;
  const int g2 = (bid & 7) * 32 + (kk >> 1);   // XCD-matched to K1
  const int sq = g2 * 16;
  const float* bias = dir ? bbw : bfw;

  bf16x8 Bf[4][4];
  const unsigned short* wl = wlstm + ((long)dir * 4096 + w * 16 * 64) * 8;
#pragma unroll
  for (int gate = 0; gate < 4; ++gate)
#pragma unroll
    for (int kf = 0; kf < 4; ++kf)
      Bf[gate][kf] = *(const bf16x8*)(wl + ((gate * 4 + kf) * 64 + l) * 8);
  float bz[4];
#pragma unroll
  for (int gate = 0; gate < 4; ++gate) bz[gate] = bias[gate * 64 + w * 16 + c];

  bf16x8 Pc[2];
#pragma unroll
  for (int kf = 0; kf < 2; ++kf)
#pragma unroll
    for (int j = 0; j < 8; ++j) Pc[kf][j] = 0;
  float bcv = 0.f;
  if (c < 8) {
#pragma unroll
    for (int kf = 0; kf < 2; ++kf)
#pragma unroll
      for (int j = 0; j < 8; ++j)
        Pc[kf][j] = (short)f2bf_hw(Wc[(kf * 32 + g * 8 + j) * 8 + c]);
    bcv = bc[c];
  }

  asm volatile("s_waitcnt vmcnt(0)" ::: "memory");

  const int ss = l >> 3, sc = l & 7;
#pragma unroll
  for (int j = 0; j < 8; ++j) {
    int tt = w * 8 + j;
    int te = dir ? 31 - tt : tt;
#pragma unroll
    for (int p = 0; p < 2; ++p) {
      int s = p * 8 + ss;
      const char* gp = (const char*)x +
          ((long)(sq + s) * 32 + te) * 128 + (long)(sc ^ (s & 7)) * 16;
      char* lp = xl + tt * 2048 + p * 1024;
      GLDS16(gp, lp);
    }
  }

  for (int i = tid; i < 1024; i += 256) ((unsigned*)hl)[i] = 0u;
  float cs[4] = {0.f, 0.f, 0.f, 0.f};

  if (w == 0) asm volatile("s_waitcnt vmcnt(12)" ::: "memory");
  asm volatile("s_waitcnt lgkmcnt(0)" ::: "memory");
  __builtin_amdgcn_s_barrier();
  __builtin_amdgcn_sched_barrier(0);

  const int hq = w >> 1;
  const int hgp = ((w & 1) * 2 + (c >> 3)) * 16;
  const int hlo = c & 7;

  f32x4 accx[4];
  {
    const char* xt = xl + 0 * 2048 + c * 128;
    bf16x8 Ax0 = *(const bf16x8*)(xt + (long)((g) ^ (c & 7)) * 16);
    bf16x8 Ax1 = *(const bf16x8*)(xt + (long)((4 + g) ^ (c & 7)) * 16);
#pragma unroll
    for (int gate = 0; gate < 4; ++gate) {
      f32x4 b = (f32x4){bz[gate], bz[gate], bz[gate], bz[gate]};
      accx[gate] = MFMA_BF16(Ax1, Bf[gate][1],
                             MFMA_BF16(Ax0, Bf[gate][0], b, 0, 0, 0), 0, 0, 0);
    }
  }
  // close the t=0 hazard window (h(0) overwrites slot 0 at step 0)
  asm volatile("s_waitcnt lgkmcnt(0)" ::: "memory");
  __builtin_amdgcn_s_barrier();
  __builtin_amdgcn_sched_barrier(0);

  int p = 0;
#pragma unroll
  for (int t = 0; t < 32; ++t) {
    bf16x8 Ah0 = *(const bf16x8*)((const char*)hl + p * 2048 + l * 16);
    bf16x8 Ah1 = *(const bf16x8*)((const char*)hl + p * 2048 + 1024 + l * 16);

    f32x4 acc[4];
#pragma unroll
    for (int gate = 0; gate < 4; ++gate)
      acc[gate] = MFMA_BF16(Ah1, Bf[gate][3],
                            MFMA_BF16(Ah0, Bf[gate][2], accx[gate], 0, 0, 0),
                            0, 0, 0);

    if (t + 1 < 32) {
      const char* xt = xl + (t + 1) * 2048 + c * 128;
      bf16x8 Ax0 = *(const bf16x8*)(xt + (long)((g) ^ (c & 7)) * 16);
      bf16x8 Ax1 = *(const bf16x8*)(xt + (long)((4 + g) ^ (c & 7)) * 16);
#pragma unroll
      for (int gate = 0; gate < 4; ++gate) {
        f32x4 b = (f32x4){bz[gate], bz[gate], bz[gate], bz[gate]};
        accx[gate] = MFMA_BF16(Ax1, Bf[gate][1],
                               MFMA_BF16(Ax0, Bf[gate][0], b, 0, 0, 0), 0, 0, 0);
      }
    }

    const int wb = (p ^ 1) * 1024;
    unsigned short* xh = (unsigned short*)xl + t * 1024;
#pragma unroll
    for (int r = 0; r < 4; ++r) {
      float ei = __expf(-acc[0][r]);
      float ej = __expf(2.f * acc[1][r]);
      float ef = __expf(-(acc[2][r] + 1.f));
      float eo = __expf(-acc[3][r]);
      float p12 = (1.f + ei) * (1.f + ej);
      float r3 = __builtin_amdgcn_rcpf(p12 * (1.f + ef));
      float it = (ej - 1.f) * (1.f + ef) * r3;
      float sf = p12 * r3;
      cs[r] = cs[r] * sf + it;
      float ec = __expf(2.f * cs[r]);
      float r2 = __builtin_amdgcn_rcpf((1.f + eo) * (1.f + ec));
      unsigned short hb = f2bf_hw((ec - 1.f) * r2);
      int off = (hq * 64 + hgp + 4 * g + r) * 8 + hlo;
      hl[wb + off] = hb;
      xh[off] = hb;
    }

    if (t + 2 < 32) {
      if (w == ((t + 2) >> 3))
        asm volatile("s_waitcnt vmcnt(%0)" :: "i"(14 - 2 * ((t + 2) & 7)) : "memory");
    }
    asm volatile("s_waitcnt lgkmcnt(0)" ::: "memory");
    __builtin_amdgcn_s_barrier();
    __builtin_amdgcn_sched_barrier(0);
    p ^= 1;
  }

  // parallel projection epilogue: wave w projects timesteps w*8..w*8+7
#pragma unroll
  for (int j = 0; j < 8; ++j) {
    int t = w * 8 + j;
    const char* hb = xl + t * 2048;
    bf16x8 Ph0 = *(const bf16x8*)(hb + l * 16);
    bf16x8 Ph1 = *(const bf16x8*)(hb + 1024 + l * 16);
    f32x4 pa = (f32x4){0.f, 0.f, 0.f, 0.f};
    pa = MFMA_BF16(Ph0, Pc[0], pa, 0, 0, 0);
    pa = MFMA_BF16(Ph1, Pc[1], pa, 0, 0, 0);
    if (c < 8) {
      int tp = dir ? 31 - t : t;
#pragma unroll
      for (int r = 0; r < 4; ++r) {
        long orow = (long)dir * 4096 + sq + 4 * g + r;
        out[(orow * 32 + tp) * 8 + c] = tanh_f(pa[r] + bcv);
      }
    }
  }
}

extern "C" void kernel_launch(void* const* d_in, const int* in_sizes, int n_in,
                              void* d_out, int out_size, void* d_ws, size_t ws_size,
                              hipStream_t stream) {
  const float* obs = (const float*)d_in[0];
  const float* W0  = (const float*)d_in[1];
  const float* b0  = (const float*)d_in[2];
  const float* gam = (const float*)d_in[3];
  const float* bet = (const float*)d_in[4];
  const float* Wfw = (const float*)d_in[5];
  const float* bfw = (const float*)d_in[6];
  const float* Wbw = (const float*)d_in[7];
  const float* bbw = (const float*)d_in[8];
  const float* Wc  = (const float*)d_in[9];
  const float* bc  = (const float*)d_in[10];
  float* out = (float*)d_out;

  unsigned short* wfrag = (unsigned short*)d_ws;       // 64 KB
  unsigned short* wlstm = wfrag + 4096 * 8;            // 128 KB
  unsigned short* xbf   = wlstm + 8192 * 8;            // 16.78 MB

  k0_conv<<<48, 256, 0, stream>>>(W0, Wfw, Wbw, wfrag, wlstm);
  k_dense_ln<<<2048, 256, 0, stream>>>(obs, wfrag, b0, gam, bet, xbf);
  k_lstm<<<512, 256, 0, stream>>>(xbf, wlstm, bfw, bbw, Wc, bc, out);
}